// Round 15
// baseline (87.879 us; speedup 1.0000x reference)
//
#include <hip/hip_runtime.h>
#include <math.h>

#define F 128
#define HID 32
#define NH 4
#define WTILE 16   // atoms per wave-chunk (wave-private)
#define ROWB 512   // bytes per fp32 row
#define PJC 4      // crystals per proj block

typedef __attribute__((ext_vector_type(8))) short bf16x8;
typedef __attribute__((ext_vector_type(4))) float f32x4;

__device__ __forceinline__ float silu_f(float x) {
    return x / (1.0f + __expf(-x));
}

__device__ __forceinline__ uint f2bf(float f) {  // RNE float->bf16 (one-time W1 prep)
    union { float f; uint u; } v; v.f = f;
    uint r = v.u + 0x7fffu + ((v.u >> 16) & 1u);
    return r >> 16;
}

__device__ __forceinline__ uint cvtpk_bf16(float lo, float hi) {  // HW RNE pack
    uint r;
    asm("v_cvt_pk_bf16_f32 %0, %1, %2" : "=v"(r) : "v"(lo), "v"(hi));
    return r;
}

// Scatter segment boundaries: starts[b] = first atom index with seg_id >= b.
__global__ void seg_starts_kernel(const int* __restrict__ seg, int* __restrict__ starts,
                                  int N, int B) {
    int i = blockIdx.x * blockDim.x + threadIdx.x;
    if (i >= N) return;
    int id = seg[i];
    if (i == 0) {
        for (int b = 0; b <= id; ++b) starts[b] = 0;
    } else {
        int prev = seg[i - 1];
        for (int b = prev + 1; b <= id; ++b) starts[b] = i;
    }
    if (i == N - 1) {
        for (int b = id + 1; b <= B; ++b) starts[b] = N;
    }
}

// One block (4 waves) per crystal; waves fully autonomous, ZERO main-loop
// barriers, NO LDS staging. Wave wv processes 16-atom chunks c = wv, wv+4, ...
//   MFMA B-frags loaded DIRECTLY from global (16 rows/instr, lg-groups share
//   the row's 128B line -> ~2x ideal address cost, not R4's 64-line scatter);
//   all 32 hids per wave -> every lane ends with all 4 head logits (no
//   cross-wave reduce); defer-max softmax private in regs; phase C re-reads
//   the same 16 rows wave-uniform (L1-resident, just fetched by this wave).
// LDS = 1 KB sTW + 8.3 KB epilogue merge -> occupancy VGPR-bound (4 blocks/CU).
__global__ __launch_bounds__(256, 2) void fused12_kernel(
    const float* __restrict__ atom_fea, const int* __restrict__ starts,
    const float* __restrict__ W1, const float* __restrict__ b1,
    const float* __restrict__ W2, const float* __restrict__ b2,
    float* __restrict__ gWacc) {
    __shared__ float sTW[NH][WTILE * NH];  // 1 KB: [wave][atom*4+head]
    __shared__ float sEpi[NH][520];        // 8.3 KB: [wave][512 acc | 4 m | 4 s]

    const int t = threadIdx.x;
    const int b = blockIdx.x;
    const int start = starts[b];
    const int end = starts[b + 1];
    const int wv = t >> 6;
    const int lane = t & 63;
    const int lg = lane >> 4;
    const int l15 = lane & 15;
    const int ch = lane & 3;    // phase C: head
    const int co = lane >> 2;   // phase C: feat-oct (feats 8co..8co+7)

    // ---- one-time register preloads (R6-verified W1T fragment layout) ----
    bf16x8 w1f[2][4];  // [h-half][k-step]; lane: h'=l15, k'=lg*8+j
    #pragma unroll
    for (int m0 = 0; m0 < 2; ++m0)
        #pragma unroll
        for (int kk = 0; kk < 4; ++kk) {
            bf16x8 fr;
            #pragma unroll
            for (int j = 0; j < 8; ++j)
                fr[j] = (short)f2bf(W1[(kk * 32 + lg * 8 + j) * HID + m0 * 16 + l15]);
            w1f[m0][kk] = fr;
        }
    float b1r[8], w2r[8][4];  // uniform -> SGPR
    #pragma unroll
    for (int m0 = 0; m0 < 2; ++m0)
        #pragma unroll
        for (int r = 0; r < 4; ++r) {
            const int h = m0 * 16 + lg * 4 + r;
            b1r[m0 * 4 + r] = b1[h];
            #pragma unroll
            for (int j = 0; j < 4; ++j) w2r[m0 * 4 + r][j] = W2[h * NH + j];
        }
    const float b2r0 = b2[0], b2r1 = b2[1], b2r2 = b2[2], b2r3 = b2[3];

    float m0_ = -INFINITY, m1_ = -INFINITY, m2_ = -INFINITY, m3_ = -INFINITY;
    float s0_ = 0.0f, s1_ = 0.0f, s2_ = 0.0f, s3_ = 0.0f;
    float acc8[8] = {0, 0, 0, 0, 0, 0, 0, 0};  // (head ch, feats 8co..+8)

    const int nc = (end > start) ? (end - start + WTILE - 1) / WTILE : 0;
    const char* gb = (const char*)atom_fea;

    for (int c = wv; c < nc; c += NH) {
        const int abase = start + c * WTILE;
        const int Tw = min(end - abase, WTILE);  // >=1 by construction

        // ---- MFMA MLP: B-frags straight from global (own 16 rows) ----
        int brow = abase + l15; brow = (brow < end) ? brow : end - 1;  // clamp
        const char* rb = gb + (size_t)brow * ROWB;
        float4 va[4], vb[4];
        #pragma unroll
        for (int kk = 0; kk < 4; ++kk) {
            va[kk] = *(const float4*)(rb + kk * 128 + lg * 32);
            vb[kk] = *(const float4*)(rb + kk * 128 + lg * 32 + 16);
        }
        f32x4 a0, a1;
        #pragma unroll
        for (int r = 0; r < 4; ++r) { a0[r] = b1r[r]; a1[r] = b1r[4 + r]; }
        #pragma unroll
        for (int kk = 0; kk < 4; ++kk) {
            union { bf16x8 v; uint u[4]; } fr;
            fr.u[0] = cvtpk_bf16(va[kk].x, va[kk].y);
            fr.u[1] = cvtpk_bf16(va[kk].z, va[kk].w);
            fr.u[2] = cvtpk_bf16(vb[kk].x, vb[kk].y);
            fr.u[3] = cvtpk_bf16(vb[kk].z, vb[kk].w);
            a0 = __builtin_amdgcn_mfma_f32_16x16x32_bf16(w1f[0][kk], fr.v, a0, 0, 0, 0);
            a1 = __builtin_amdgcn_mfma_f32_16x16x32_bf16(w1f[1][kk], fr.v, a1, 0, 0, 0);
        }

        // ---- silu + W2; lg-group reduce -> every lane: all 4 head logits ----
        float p0 = 0, p1 = 0, p2 = 0, p3 = 0;
        #pragma unroll
        for (int r = 0; r < 4; ++r) {
            const float sa = silu_f(a0[r]);
            const float sb = silu_f(a1[r]);
            p0 = fmaf(sa, w2r[r][0], fmaf(sb, w2r[4 + r][0], p0));
            p1 = fmaf(sa, w2r[r][1], fmaf(sb, w2r[4 + r][1], p1));
            p2 = fmaf(sa, w2r[r][2], fmaf(sb, w2r[4 + r][2], p2));
            p3 = fmaf(sa, w2r[r][3], fmaf(sb, w2r[4 + r][3], p3));
        }
        p0 += __shfl_xor(p0, 16); p0 += __shfl_xor(p0, 32);
        p1 += __shfl_xor(p1, 16); p1 += __shfl_xor(p1, 32);
        p2 += __shfl_xor(p2, 16); p2 += __shfl_xor(p2, 32);
        p3 += __shfl_xor(p3, 16); p3 += __shfl_xor(p3, 32);
        const bool valid = (l15 < Tw);
        const float v0 = valid ? p0 + b2r0 : -INFINITY;
        const float v1 = valid ? p1 + b2r1 : -INFINITY;
        const float v2 = valid ? p2 + b2r2 : -INFINITY;
        const float v3 = valid ? p3 + b2r3 : -INFINITY;

        // ---- defer-max (T13), wave-private ----
        const float dm = fmaxf(fmaxf(v0 - m0_, v1 - m1_), fmaxf(v2 - m2_, v3 - m3_));
        if (__any(dm > 8.0f)) {  // first chunk + rare growth
            float t0 = v0, t1 = v1, t2 = v2, t3 = v3;
            #pragma unroll
            for (int d = 1; d < 16; d <<= 1) {
                t0 = fmaxf(t0, __shfl_xor(t0, d));
                t1 = fmaxf(t1, __shfl_xor(t1, d));
                t2 = fmaxf(t2, __shfl_xor(t2, d));
                t3 = fmaxf(t3, __shfl_xor(t3, d));
            }
            const float n0 = fmaxf(m0_, t0), n1 = fmaxf(m1_, t1);
            const float n2 = fmaxf(m2_, t2), n3 = fmaxf(m3_, t3);
            const float r0 = __expf(m0_ - n0), r1 = __expf(m1_ - n1);
            const float r2 = __expf(m2_ - n2), r3 = __expf(m3_ - n3);
            s0_ *= r0; s1_ *= r1; s2_ *= r2; s3_ *= r3;
            m0_ = n0; m1_ = n1; m2_ = n2; m3_ = n3;
            const float rsel = (ch & 1) ? ((ch & 2) ? r3 : r1)
                                        : ((ch & 2) ? r2 : r0);
            #pragma unroll
            for (int j = 0; j < 8; ++j) acc8[j] *= rsel;
        }
        const float e0 = valid ? __expf(v0 - m0_) : 0.0f;  // bounded by e^8
        const float e1 = valid ? __expf(v1 - m1_) : 0.0f;
        const float e2 = valid ? __expf(v2 - m2_) : 0.0f;
        const float e3 = valid ? __expf(v3 - m3_) : 0.0f;
        s0_ += e0; s1_ += e1; s2_ += e2; s3_ += e3;  // 4x lg-replicated; /4 at end
        if (lane < 16) *(float4*)&sTW[wv][lane * NH] = make_float4(e0, e1, e2, e3);

        // ---- phase C: weighted accumulate; rows re-read wave-uniform (L1-hot) ----
        #pragma unroll 4
        for (int a = 0; a < WTILE; ++a) {
            const float w = sTW[wv][a * NH + ch];  // invalid atoms hold 0
            int arow = abase + a; arow = (arow < end) ? arow : end - 1;
            const char* ra = gb + (size_t)arow * ROWB;
            const float4 q0 = *(const float4*)(ra + co * 32);
            const float4 q1 = *(const float4*)(ra + co * 32 + 16);
            acc8[0] = fmaf(w, q0.x, acc8[0]);
            acc8[1] = fmaf(w, q0.y, acc8[1]);
            acc8[2] = fmaf(w, q0.z, acc8[2]);
            acc8[3] = fmaf(w, q0.w, acc8[3]);
            acc8[4] = fmaf(w, q1.x, acc8[4]);
            acc8[5] = fmaf(w, q1.y, acc8[5]);
            acc8[6] = fmaf(w, q1.z, acc8[6]);
            acc8[7] = fmaf(w, q1.w, acc8[7]);
        }
    }

    // ---- epilogue: merge 4 autonomous waves (single barrier) ----
    #pragma unroll
    for (int d = 1; d < 64; d <<= 1) {
        s0_ += __shfl_xor(s0_, d); s1_ += __shfl_xor(s1_, d);
        s2_ += __shfl_xor(s2_, d); s3_ += __shfl_xor(s3_, d);
    }
    *(float4*)&sEpi[wv][lane * 8] = make_float4(acc8[0], acc8[1], acc8[2], acc8[3]);
    *(float4*)&sEpi[wv][lane * 8 + 4] = make_float4(acc8[4], acc8[5], acc8[6], acc8[7]);
    if (lane == 0) {
        sEpi[wv][512] = m0_; sEpi[wv][513] = m1_;
        sEpi[wv][514] = m2_; sEpi[wv][515] = m3_;
        sEpi[wv][516] = s0_ * 0.25f; sEpi[wv][517] = s1_ * 0.25f;
        sEpi[wv][518] = s2_ * 0.25f; sEpi[wv][519] = s3_ * 0.25f;
    }
    __syncthreads();
    if (t < 64) {
        const int ch2 = t & 3, co2 = t >> 2;
        float mw[NH], fw[NH];
        float mg = -INFINITY;
        #pragma unroll
        for (int w = 0; w < NH; ++w) {
            mw[w] = sEpi[w][512 + ch2];
            mg = fmaxf(mg, mw[w]);
        }
        float sg = 0.0f;
        #pragma unroll
        for (int w = 0; w < NH; ++w) {
            fw[w] = (mw[w] == -INFINITY) ? 0.0f : __expf(mw[w] - mg);
            sg += sEpi[w][516 + ch2] * fw[w];
        }
        const float inv = (sg > 0.0f) ? 1.0f / sg : 0.0f;
        float o[8] = {0, 0, 0, 0, 0, 0, 0, 0};
        #pragma unroll
        for (int w = 0; w < NH; ++w) {
            const float* ap = &sEpi[w][t * 8];
            #pragma unroll
            for (int j = 0; j < 8; ++j) o[j] = fmaf(ap[j], fw[w], o[j]);
        }
        float* dst = &gWacc[(size_t)b * 512 + ch2 * F + co2 * 8];
        *(float4*)dst = make_float4(o[0] * inv, o[1] * inv, o[2] * inv, o[3] * inv);
        *(float4*)(dst + 4) = make_float4(o[4] * inv, o[5] * inv, o[6] * inv, o[7] * inv);
    }
}

// K4: out[b] = silu(Wacc[b] @ Wp + bp). PJC crystals per block; 8-deep Wp
// load batching.
__global__ __launch_bounds__(256) void proj_kernel(
    const float* __restrict__ gWacc, const float* __restrict__ Wp,
    const float* __restrict__ bp, float* __restrict__ out, int B) {
    __shared__ float sW[PJC * 512];
    __shared__ float sP[256 * PJC];
    const int t = threadIdx.x;
    const int c0 = blockIdx.x * PJC;
    for (int q = t; q < PJC * 512; q += 256) {
        const int cr = c0 + (q >> 9);
        sW[q] = (cr < B) ? gWacc[(size_t)cr * 512 + (q & 511)] : 0.0f;
    }
    __syncthreads();
    const int f = t & 127, half = t >> 7;
    float acc[PJC] = {};
    const float* wp = Wp + (size_t)(half * 256) * F + f;
    for (int k0 = 0; k0 < 256; k0 += 8) {
        float wpv[8];
        #pragma unroll
        for (int u = 0; u < 8; ++u) wpv[u] = wp[(size_t)(k0 + u) * F];
        #pragma unroll
        for (int u = 0; u < 8; ++u) {
            const int ks = half * 256 + k0 + u;
            #pragma unroll
            for (int g = 0; g < PJC; ++g) acc[g] = fmaf(sW[g * 512 + ks], wpv[u], acc[g]);
        }
    }
    #pragma unroll
    for (int g = 0; g < PJC; ++g) sP[t * PJC + g] = acc[g];
    __syncthreads();
    if (t < 128) {
        const float bpf = bp[t];
        #pragma unroll
        for (int g = 0; g < PJC; ++g) {
            const int cr = c0 + g;
            if (cr < B)
                out[(size_t)cr * F + t] =
                    silu_f(sP[t * PJC + g] + sP[(t + 128) * PJC + g] + bpf);
        }
    }
}

extern "C" void kernel_launch(void* const* d_in, const int* in_sizes, int n_in,
                              void* d_out, int out_size, void* d_ws, size_t ws_size,
                              hipStream_t stream) {
    const float* atom_fea = (const float*)d_in[0];
    const int* seg = (const int*)d_in[1];
    const float* W1 = (const float*)d_in[3];
    const float* b1 = (const float*)d_in[4];
    const float* W2 = (const float*)d_in[5];
    const float* b2 = (const float*)d_in[6];
    const float* Wp = (const float*)d_in[7];
    const float* bp = (const float*)d_in[8];
    float* out = (float*)d_out;

    const int N = in_sizes[0] / F;
    const int B = out_size / F;

    // ws layout: starts[B+1] | Wacc[B*512]
    char* ws = (char*)d_ws;
    int* starts = (int*)ws;
    size_t off = (((size_t)(B + 1) * sizeof(int)) + 255) & ~(size_t)255;
    float* gWacc = (float*)(ws + off);

    seg_starts_kernel<<<(N + 255) / 256, 256, 0, stream>>>(seg, starts, N, B);
    fused12_kernel<<<B, 256, 0, stream>>>(atom_fea, starts, W1, b1, W2, b2, gWacc);
    proj_kernel<<<(B + PJC - 1) / PJC, 256, 0, stream>>>(gWacc, Wp, bp, out, B);
}

// Round 16
// 71.943 us; speedup vs baseline: 1.2215x; 1.2215x over previous
//
#include <hip/hip_runtime.h>
#include <math.h>

#define F 128
#define HID 32
#define NH 4
#define TILE 32
#define ROWB 512  // bytes per fp32 row (128 * 4)
#define PJC 4     // crystals per proj block
#define PSLOT 520 // floats per half-partial: 512 acc + 4 m + 4 s

typedef __attribute__((ext_vector_type(8))) short bf16x8;
typedef __attribute__((ext_vector_type(4))) float f32x4;

__device__ __forceinline__ float silu_f(float x) {
    return x / (1.0f + __expf(-x));
}

__device__ __forceinline__ uint f2bf(float f) {  // RNE float->bf16 (one-time W1 prep)
    union { float f; uint u; } v; v.f = f;
    uint r = v.u + 0x7fffu + ((v.u >> 16) & 1u);
    return r >> 16;
}

__device__ __forceinline__ uint cvtpk_bf16(float lo, float hi) {  // HW RNE pack
    uint r;
    asm("v_cvt_pk_bf16_f32 %0, %1, %2" : "=v"(r) : "v"(lo), "v"(hi));
    return r;
}

__device__ __forceinline__ void gload_lds16(const void* g, void* l) {
    // async 16B global->LDS; LDS dest is wave-uniform base + lane*16
    __builtin_amdgcn_global_load_lds(
        (const __attribute__((address_space(1))) void*)g,
        (__attribute__((address_space(3))) void*)l, 16, 0, 0);
}

// Scatter segment boundaries: starts[b] = first atom index with seg_id >= b.
__global__ void seg_starts_kernel(const int* __restrict__ seg, int* __restrict__ starts,
                                  int N, int B) {
    int i = blockIdx.x * blockDim.x + threadIdx.x;
    if (i >= N) return;
    int id = seg[i];
    if (i == 0) {
        for (int b = 0; b <= id; ++b) starts[b] = 0;
    } else {
        int prev = seg[i - 1];
        for (int b = prev + 1; b <= id; ++b) starts[b] = i;
    }
    if (i == N - 1) {
        for (int b = id + 1; b <= B; ++b) starts[b] = N;
    }
}

// R12's fused9 structure (best measured: 64.7 us wall), with ONE change:
// each block processes HALF a crystal (grid = 2B) and writes an unnormalized
// partial (acc[512], m[4], s[4]) -> proj merges halves with max-alignment.
// Halves the per-block serial tile chain (~6.25 -> ~3.1 tiles), doubles the
// number of independent blocks interleaving per CU.
__global__ __launch_bounds__(256, 4) void fused13_kernel(
    const float* __restrict__ atom_fea, const int* __restrict__ starts,
    const float* __restrict__ W1, const float* __restrict__ b1,
    const float* __restrict__ W2, const float* __restrict__ b2,
    float* __restrict__ gPart) {
    __shared__ float sStage[2][TILE * F];  // 2 x 16 KB, 16B-chunk XOR swizzle (^ row&7)
    __shared__ float sP[2 * TILE * 5];     // partial logits [half][atom][head], stride 5
    __shared__ float sTW[NH * 65];         // exp weights [head][atom]

    const int t = threadIdx.x;
    const int bid = blockIdx.x;
    const int b = bid >> 1;
    const int half = bid & 1;
    const int s0 = starts[b];
    const int e0 = starts[b + 1];
    const int len = e0 - s0;
    const int hl = (len + 1) >> 1;
    const int start = half ? (s0 + hl) : s0;
    const int end = half ? e0 : (s0 + hl);

    const int wv = t >> 6;
    const int lane = t & 63;
    const int lg = lane >> 4;
    const int l15 = lane & 15;
    const int ag = wv & 1;        // MFMA atom-group (atoms 16ag..16ag+15)
    const int mh = wv >> 1;       // MFMA hid-half (hids 16mh..16mh+15)
    const int ca = lane & 3;      // phase-C atom offset within quad
    const int co = (lane >> 2) & 15;  // phase-C feat-oct (feats 8co..8co+7)

    // per-thread DMA slots: slot q holds LDS chunk (r, q&31) from global chunk
    // (q&31)^(r&7) of row r (inverse swizzle; read-side XOR recovers linear)
    int roff[4], coff[4];
    #pragma unroll
    for (int i = 0; i < 4; ++i) {
        const int q = i * 256 + t;
        roff[i] = q >> 5;
        coff[i] = ((q & 31) ^ (roff[i] & 7)) << 4;
    }

    // ---- one-time register preloads: only this wave's hid-half of W1T ----
    bf16x8 w1f[4];  // [k-step]; lane: h'=l15 (of half mh), k'=lg*8+j
    #pragma unroll
    for (int kk = 0; kk < 4; ++kk) {
        bf16x8 fr;
        #pragma unroll
        for (int j = 0; j < 8; ++j)
            fr[j] = (short)f2bf(W1[(kk * 32 + lg * 8 + j) * HID + mh * 16 + l15]);
        w1f[kk] = fr;
    }
    float b1r[4], w2r[4][4];
    #pragma unroll
    for (int r = 0; r < 4; ++r) {
        const int h = mh * 16 + lg * 4 + r;
        b1r[r] = b1[h];
        #pragma unroll
        for (int j = 0; j < 4; ++j) w2r[r][j] = W2[h * NH + j];
    }
    const float b2w = b2[wv];

    float m_run = -INFINITY;
    float s_part = 0.0f;  // per-lane deferred denominator partial
    float acc8[8] = {0, 0, 0, 0, 0, 0, 0, 0};  // head wv, feats 8co..+8, atoms ca mod 4

    const int nt = (end > start) ? (end - start + TILE - 1) / TILE : 0;
    const char* gbase = (const char*)atom_fea;

    // ---- prologue: DMA tile 0 into buf0 ----
    if (nt > 0) {
        #pragma unroll
        for (int i = 0; i < 4; ++i) {
            int a = start + roff[i]; a = (a < end) ? a : end - 1;  // clamp rows
            gload_lds16(gbase + (size_t)a * ROWB + coff[i],
                        (char*)sStage[0] + i * 4096 + wv * 1024);
        }
    }
    __syncthreads();  // drains vmcnt(0): tile 0 staged

    int pb = 0;
    for (int ti = 0; ti < nt; ++ti) {
        const int base = start + ti * TILE;
        const int T = min(TILE, end - base);
        const char* bufc = (const char*)sStage[pb];
        const bool has_next = (ti + 1 < nt);  // block-uniform

        // ---- issue DMA(k+1) into alternate buffer: in flight the WHOLE tile ----
        if (has_next) {
            const int nbase = base + TILE;
            char* ldst = (char*)sStage[pb ^ 1];
            #pragma unroll
            for (int i = 0; i < 4; ++i) {
                int a = nbase + roff[i]; a = (a < end) ? a : end - 1;
                gload_lds16(gbase + (size_t)a * ROWB + coff[i],
                            ldst + i * 4096 + wv * 1024);
            }
        }

        // ---- B: MFMA MLP; wave (ag, mh): atoms 16ag..+16, hids 16mh..+16 ----
        {
            f32x4 acc;
            #pragma unroll
            for (int r = 0; r < 4; ++r) acc[r] = b1r[r];
            const int row = ag * 16 + l15;
            const char* rb = bufc + row * ROWB;
            const int rs = row & 7;
            #pragma unroll
            for (int kk = 0; kk < 4; ++kk) {
                const int c0 = kk * 8 + lg * 2;
                const float4 va = *(const float4*)(rb + ((c0 ^ rs) << 4));
                const float4 vb = *(const float4*)(rb + (((c0 + 1) ^ rs) << 4));
                union { bf16x8 v; uint u[4]; } fr;
                fr.u[0] = cvtpk_bf16(va.x, va.y);
                fr.u[1] = cvtpk_bf16(va.z, va.w);
                fr.u[2] = cvtpk_bf16(vb.x, vb.y);
                fr.u[3] = cvtpk_bf16(vb.z, vb.w);
                acc = __builtin_amdgcn_mfma_f32_16x16x32_bf16(w1f[kk], fr.v, acc, 0, 0, 0);
            }
            // silu + W2 partial over this wave's 16 hids (4 per lane, 4 lg groups)
            float p0 = 0, p1 = 0, p2 = 0, p3 = 0;
            #pragma unroll
            for (int r = 0; r < 4; ++r) {
                const float s = silu_f(acc[r]);
                p0 = fmaf(s, w2r[r][0], p0);
                p1 = fmaf(s, w2r[r][1], p1);
                p2 = fmaf(s, w2r[r][2], p2);
                p3 = fmaf(s, w2r[r][3], p3);
            }
            p0 += __shfl_xor(p0, 16); p0 += __shfl_xor(p0, 32);
            p1 += __shfl_xor(p1, 16); p1 += __shfl_xor(p1, 32);
            p2 += __shfl_xor(p2, 16); p2 += __shfl_xor(p2, 32);
            p3 += __shfl_xor(p3, 16); p3 += __shfl_xor(p3, 32);
            if (lane < 16) {
                float* d = &sP[(mh * TILE + ag * 16 + lane) * 5];
                d[0] = p0; d[1] = p1; d[2] = p2; d[3] = p3;
            }
        }
        // bar1: LDS-only fence (NO vmcnt drain -> DMA keeps streaming)
        asm volatile("s_waitcnt lgkmcnt(0)" ::: "memory");
        __builtin_amdgcn_s_barrier();

        // ---- D: defer-max online softmax (T13); wave wv = head wv, lane = atom ----
        {
            const float v = (lane < T)
                ? sP[lane * 5 + wv] + sP[(TILE + lane) * 5 + wv] + b2w
                : -INFINITY;
            if (__any(v > m_run + 8.0f)) {  // wave-uniform; rare after tile 0
                float mt = v;
                #pragma unroll
                for (int d = 1; d < 64; d <<= 1) mt = fmaxf(mt, __shfl_xor(mt, d));
                const float m_new = fmaxf(m_run, mt);
                const float r = __expf(m_run - m_new);  // first tile: exp(-inf)=0
                s_part *= r;
                #pragma unroll
                for (int j = 0; j < 8; ++j) acc8[j] *= r;
                m_run = m_new;
            }
            const float e = (lane < T) ? __expf(v - m_run) : 0.0f;  // bounded by e^8
            sTW[wv * 65 + lane] = e;  // own-wave region; same-wave read below
            s_part += e;
        }

        // ---- C: fp32 weighted accumulate; lane = (atom-off ca, oct co) ----
        {
            #pragma unroll 4
            for (int i = 0; i < 8; ++i) {
                const int a = i * 4 + ca;
                const float w = sTW[wv * 65 + a];
                const int sw = a & 7;
                const char* ra = bufc + a * ROWB;
                const float4 v0 = *(const float4*)(ra + (((2 * co) ^ sw) << 4));
                const float4 v1 = *(const float4*)(ra + (((2 * co + 1) ^ sw) << 4));
                acc8[0] = fmaf(w, v0.x, acc8[0]);
                acc8[1] = fmaf(w, v0.y, acc8[1]);
                acc8[2] = fmaf(w, v0.z, acc8[2]);
                acc8[3] = fmaf(w, v0.w, acc8[3]);
                acc8[4] = fmaf(w, v1.x, acc8[4]);
                acc8[5] = fmaf(w, v1.y, acc8[5]);
                acc8[6] = fmaf(w, v1.z, acc8[6]);
                acc8[7] = fmaf(w, v1.w, acc8[7]);
            }
        }
        __syncthreads();  // drains vmcnt(0): DMA(k+1) landed; buf[pb] reads done
        pb ^= 1;
    }

    // ---- epilogue: denom butterfly + UNNORMALIZED partial store ----
    #pragma unroll
    for (int d = 1; d < 64; d <<= 1) s_part += __shfl_xor(s_part, d);
    #pragma unroll
    for (int j = 0; j < 8; ++j) {
        acc8[j] += __shfl_xor(acc8[j], 1);
        acc8[j] += __shfl_xor(acc8[j], 2);
    }
    float* slot = &gPart[(size_t)bid * PSLOT];
    if ((lane & 3) == 0) {
        float* dst = slot + wv * F + (lane >> 2) * 8;
        *(float4*)dst = make_float4(acc8[0], acc8[1], acc8[2], acc8[3]);
        *(float4*)(dst + 4) = make_float4(acc8[4], acc8[5], acc8[6], acc8[7]);
    }
    if (lane == 0) {
        slot[512 + wv] = m_run;
        slot[516 + wv] = s_part;
    }
}

// K4: merge the two half-partials per crystal (max-aligned), normalize, then
// out[b] = silu(Wacc[b] @ Wp + bp). PJC crystals per block.
__global__ __launch_bounds__(256) void proj2_kernel(
    const float* __restrict__ gPart, const float* __restrict__ Wp,
    const float* __restrict__ bp, float* __restrict__ out, int B) {
    __shared__ float sRaw[PJC][2][PSLOT];  // 16.6 KB
    __shared__ float sW[PJC * 512];        // 8 KB merged+normalized Wacc
    __shared__ float sP[256 * PJC];        // 4 KB
    const int t = threadIdx.x;
    const int c0 = blockIdx.x * PJC;

    for (int q = t; q < PJC * 2 * PSLOT; q += 256) {
        const int g = q / (2 * PSLOT);
        const int rem = q - g * 2 * PSLOT;
        const int hf = rem / PSLOT;
        const int k = rem - hf * PSLOT;
        const int cr = c0 + g;
        sRaw[g][hf][k] = (cr < B) ? gPart[(size_t)(cr * 2 + hf) * PSLOT + k] : 0.0f;
    }
    __syncthreads();

    for (int q = t; q < PJC * 512; q += 256) {
        const int g = q >> 9;
        const int k = q & 511;
        const int h = k >> 7;
        const float m0 = sRaw[g][0][512 + h], m1 = sRaw[g][1][512 + h];
        const float mg = fmaxf(m0, m1);
        const float f0 = (m0 == -INFINITY) ? 0.0f : __expf(m0 - mg);
        const float f1 = (m1 == -INFINITY) ? 0.0f : __expf(m1 - mg);
        const float sg = sRaw[g][0][516 + h] * f0 + sRaw[g][1][516 + h] * f1;
        const float inv = (sg > 0.0f) ? 1.0f / sg : 0.0f;
        sW[q] = (sRaw[g][0][k] * f0 + sRaw[g][1][k] * f1) * inv;
    }
    __syncthreads();

    const int f = t & 127, half = t >> 7;
    float acc[PJC] = {};
    const float* wp = Wp + (size_t)(half * 256) * F + f;
    for (int k0 = 0; k0 < 256; k0 += 8) {
        float wpv[8];
        #pragma unroll
        for (int u = 0; u < 8; ++u) wpv[u] = wp[(size_t)(k0 + u) * F];
        #pragma unroll
        for (int u = 0; u < 8; ++u) {
            const int ks = half * 256 + k0 + u;  // wave-uniform -> LDS broadcast
            #pragma unroll
            for (int g = 0; g < PJC; ++g) acc[g] = fmaf(sW[g * 512 + ks], wpv[u], acc[g]);
        }
    }
    #pragma unroll
    for (int g = 0; g < PJC; ++g) sP[t * PJC + g] = acc[g];
    __syncthreads();
    if (t < 128) {
        const float bpf = bp[t];
        #pragma unroll
        for (int g = 0; g < PJC; ++g) {
            const int cr = c0 + g;
            if (cr < B)
                out[(size_t)cr * F + t] =
                    silu_f(sP[t * PJC + g] + sP[(t + 128) * PJC + g] + bpf);
        }
    }
}

extern "C" void kernel_launch(void* const* d_in, const int* in_sizes, int n_in,
                              void* d_out, int out_size, void* d_ws, size_t ws_size,
                              hipStream_t stream) {
    const float* atom_fea = (const float*)d_in[0];
    const int* seg = (const int*)d_in[1];
    const float* W1 = (const float*)d_in[3];
    const float* b1 = (const float*)d_in[4];
    const float* W2 = (const float*)d_in[5];
    const float* b2 = (const float*)d_in[6];
    const float* Wp = (const float*)d_in[7];
    const float* bp = (const float*)d_in[8];
    float* out = (float*)d_out;

    const int N = in_sizes[0] / F;
    const int B = out_size / F;

    // ws layout: starts[B+1] | gPart[2B * PSLOT]
    char* ws = (char*)d_ws;
    int* starts = (int*)ws;
    size_t off = (((size_t)(B + 1) * sizeof(int)) + 255) & ~(size_t)255;
    float* gPart = (float*)(ws + off);

    seg_starts_kernel<<<(N + 255) / 256, 256, 0, stream>>>(seg, starts, N, B);
    fused13_kernel<<<2 * B, 256, 0, stream>>>(atom_fea, starts, W1, b1, W2, b2, gPart);
    proj2_kernel<<<(B + PJC - 1) / PJC, 256, 0, stream>>>(gPart, Wp, bp, out, B);
}

// Round 17
// 65.929 us; speedup vs baseline: 1.3329x; 1.0912x over previous
//
#include <hip/hip_runtime.h>
#include <math.h>

#define F 128
#define HID 32
#define NH 4
#define TILE 32
#define ROWB 512  // bytes per fp32 row (128 * 4)
#define PJC 4     // crystals per proj block

typedef __attribute__((ext_vector_type(8))) short bf16x8;
typedef __attribute__((ext_vector_type(4))) float f32x4;

__device__ __forceinline__ float silu_f(float x) {
    return x / (1.0f + __expf(-x));
}

__device__ __forceinline__ uint f2bf(float f) {  // RNE float->bf16 (one-time W1 prep)
    union { float f; uint u; } v; v.f = f;
    uint r = v.u + 0x7fffu + ((v.u >> 16) & 1u);
    return r >> 16;
}

__device__ __forceinline__ uint cvtpk_bf16(float lo, float hi) {  // HW RNE pack
    uint r;
    asm("v_cvt_pk_bf16_f32 %0, %1, %2" : "=v"(r) : "v"(lo), "v"(hi));
    return r;
}

__device__ __forceinline__ void gload_lds16(const void* g, void* l) {
    // async 16B global->LDS; LDS dest is wave-uniform base + lane*16
    __builtin_amdgcn_global_load_lds(
        (const __attribute__((address_space(1))) void*)g,
        (__attribute__((address_space(3))) void*)l, 16, 0, 0);
}

// Scatter segment boundaries: starts[b] = first atom index with seg_id >= b.
__global__ void seg_starts_kernel(const int* __restrict__ seg, int* __restrict__ starts,
                                  int N, int B) {
    int i = blockIdx.x * blockDim.x + threadIdx.x;
    if (i >= N) return;
    int id = seg[i];
    if (i == 0) {
        for (int b = 0; b <= id; ++b) starts[b] = 0;
    } else {
        int prev = seg[i - 1];
        for (int b = prev + 1; b <= id; ++b) starts[b] = i;
    }
    if (i == N - 1) {
        for (int b = id + 1; b <= B; ++b) starts[b] = N;
    }
}

// R12's fused9 (best: 64.7 us) with ONE change (T4, counted vmcnt):
// TRIPLE-buffered stage; DMA(k+2) issued at top of tile k; end-of-tile wait is
// s_waitcnt vmcnt(4) + lgkmcnt(0) + RAW s_barrier (never vmcnt(0) mid-loop).
// Each tile's DMA gets ~2 tile-times to land instead of ~1 -> drain stall gone.
__global__ __launch_bounds__(256, 4) void fused14_kernel(
    const float* __restrict__ atom_fea, const int* __restrict__ starts,
    const float* __restrict__ W1, const float* __restrict__ b1,
    const float* __restrict__ W2, const float* __restrict__ b2,
    float* __restrict__ gWacc) {
    __shared__ float sStage[3][TILE * F];  // 3 x 16 KB, 16B-chunk XOR swizzle (^ row&7)
    __shared__ float sP[2 * TILE * 5];     // partial logits [half][atom][head], stride 5
    __shared__ float sTW[NH * 65];         // exp weights [head][atom]

    const int t = threadIdx.x;
    const int b = blockIdx.x;
    const int start = starts[b];
    const int end = starts[b + 1];
    const int wv = t >> 6;
    const int lane = t & 63;
    const int lg = lane >> 4;
    const int l15 = lane & 15;
    const int ag = wv & 1;        // MFMA atom-group (atoms 16ag..16ag+15)
    const int mh = wv >> 1;       // MFMA hid-half (hids 16mh..16mh+15)
    const int ca = lane & 3;      // phase-C atom offset within quad
    const int co = (lane >> 2) & 15;  // phase-C feat-oct (feats 8co..8co+7)

    // per-thread DMA slots: slot q holds LDS chunk (r, q&31) from global chunk
    // (q&31)^(r&7) of row r (inverse swizzle; read-side XOR recovers linear)
    int roff[4], coff[4];
    #pragma unroll
    for (int i = 0; i < 4; ++i) {
        const int q = i * 256 + t;
        roff[i] = q >> 5;
        coff[i] = ((q & 31) ^ (roff[i] & 7)) << 4;
    }

    // ---- one-time register preloads: only this wave's hid-half of W1T ----
    bf16x8 w1f[4];  // [k-step]; lane: h'=l15 (of half mh), k'=lg*8+j
    #pragma unroll
    for (int kk = 0; kk < 4; ++kk) {
        bf16x8 fr;
        #pragma unroll
        for (int j = 0; j < 8; ++j)
            fr[j] = (short)f2bf(W1[(kk * 32 + lg * 8 + j) * HID + mh * 16 + l15]);
        w1f[kk] = fr;
    }
    float b1r[4], w2r[4][4];
    #pragma unroll
    for (int r = 0; r < 4; ++r) {
        const int h = mh * 16 + lg * 4 + r;
        b1r[r] = b1[h];
        #pragma unroll
        for (int j = 0; j < 4; ++j) w2r[r][j] = W2[h * NH + j];
    }
    const float b2w = b2[wv];

    float m_run = -INFINITY;
    float s_part = 0.0f;  // per-lane deferred denominator partial
    float acc8[8] = {0, 0, 0, 0, 0, 0, 0, 0};  // head wv, feats 8co..+8, atoms ca mod 4

    const int nt = (end > start) ? (end - start + TILE - 1) / TILE : 0;
    const char* gbase = (const char*)atom_fea;

    // ---- prologue: pipeline tiles 0 and 1 ----
    if (nt > 0) {
        #pragma unroll
        for (int i = 0; i < 4; ++i) {
            int a = start + roff[i]; a = (a < end) ? a : end - 1;  // clamp rows
            gload_lds16(gbase + (size_t)a * ROWB + coff[i],
                        (char*)sStage[0] + i * 4096 + wv * 1024);
        }
    }
    if (nt > 1) {
        #pragma unroll
        for (int i = 0; i < 4; ++i) {
            int a = start + TILE + roff[i]; a = (a < end) ? a : end - 1;
            gload_lds16(gbase + (size_t)a * ROWB + coff[i],
                        (char*)sStage[1] + i * 4096 + wv * 1024);
        }
        asm volatile("s_waitcnt vmcnt(4)" ::: "memory");  // tile 0 landed
    } else {
        asm volatile("s_waitcnt vmcnt(0)" ::: "memory");
    }
    __builtin_amdgcn_s_barrier();

    int cur = 0;  // buffer index of tile ti (rotates 0,1,2)
    for (int ti = 0; ti < nt; ++ti) {
        const int base = start + ti * TILE;
        const int T = min(TILE, end - base);
        const char* bufc = (const char*)sStage[cur];
        const int nx2 = (cur == 0) ? 2 : (cur - 1);  // (cur+2)%3

        // ---- issue DMA(ti+2) into buffer nx2 (in flight ~2 tiles) ----
        const bool has2 = (ti + 2 < nt);  // block-uniform
        if (has2) {
            const int nbase = base + 2 * TILE;
            char* ldst = (char*)sStage[nx2];
            #pragma unroll
            for (int i = 0; i < 4; ++i) {
                int a = nbase + roff[i]; a = (a < end) ? a : end - 1;
                gload_lds16(gbase + (size_t)a * ROWB + coff[i],
                            ldst + i * 4096 + wv * 1024);
            }
        }

        // ---- B: MFMA MLP; wave (ag, mh): atoms 16ag..+16, hids 16mh..+16 ----
        {
            f32x4 acc;
            #pragma unroll
            for (int r = 0; r < 4; ++r) acc[r] = b1r[r];
            const int row = ag * 16 + l15;
            const char* rb = bufc + row * ROWB;
            const int rs = row & 7;
            #pragma unroll
            for (int kk = 0; kk < 4; ++kk) {
                const int c0 = kk * 8 + lg * 2;
                const float4 va = *(const float4*)(rb + ((c0 ^ rs) << 4));
                const float4 vb = *(const float4*)(rb + (((c0 + 1) ^ rs) << 4));
                union { bf16x8 v; uint u[4]; } fr;
                fr.u[0] = cvtpk_bf16(va.x, va.y);
                fr.u[1] = cvtpk_bf16(va.z, va.w);
                fr.u[2] = cvtpk_bf16(vb.x, vb.y);
                fr.u[3] = cvtpk_bf16(vb.z, vb.w);
                acc = __builtin_amdgcn_mfma_f32_16x16x32_bf16(w1f[kk], fr.v, acc, 0, 0, 0);
            }
            // silu + W2 partial over this wave's 16 hids (4 per lane, 4 lg groups)
            float p0 = 0, p1 = 0, p2 = 0, p3 = 0;
            #pragma unroll
            for (int r = 0; r < 4; ++r) {
                const float s = silu_f(acc[r]);
                p0 = fmaf(s, w2r[r][0], p0);
                p1 = fmaf(s, w2r[r][1], p1);
                p2 = fmaf(s, w2r[r][2], p2);
                p3 = fmaf(s, w2r[r][3], p3);
            }
            p0 += __shfl_xor(p0, 16); p0 += __shfl_xor(p0, 32);
            p1 += __shfl_xor(p1, 16); p1 += __shfl_xor(p1, 32);
            p2 += __shfl_xor(p2, 16); p2 += __shfl_xor(p2, 32);
            p3 += __shfl_xor(p3, 16); p3 += __shfl_xor(p3, 32);
            if (lane < 16) {
                float* d = &sP[(mh * TILE + ag * 16 + lane) * 5];
                d[0] = p0; d[1] = p1; d[2] = p2; d[3] = p3;
            }
        }
        // bar1: LDS-only fence (NO vmcnt drain -> DMA keeps streaming)
        asm volatile("s_waitcnt lgkmcnt(0)" ::: "memory");
        __builtin_amdgcn_s_barrier();

        // ---- D: defer-max online softmax (T13); wave wv = head wv, lane = atom ----
        {
            const float v = (lane < T)
                ? sP[lane * 5 + wv] + sP[(TILE + lane) * 5 + wv] + b2w
                : -INFINITY;
            if (__any(v > m_run + 8.0f)) {  // wave-uniform; rare after tile 0
                float mt = v;
                #pragma unroll
                for (int d = 1; d < 64; d <<= 1) mt = fmaxf(mt, __shfl_xor(mt, d));
                const float m_new = fmaxf(m_run, mt);
                const float r = __expf(m_run - m_new);  // first tile: exp(-inf)=0
                s_part *= r;
                #pragma unroll
                for (int j = 0; j < 8; ++j) acc8[j] *= r;
                m_run = m_new;
            }
            const float e = (lane < T) ? __expf(v - m_run) : 0.0f;  // bounded by e^8
            sTW[wv * 65 + lane] = e;  // own-wave region; same-wave read below
            s_part += e;
        }

        // ---- C: fp32 weighted accumulate; lane = (atom-off ca, oct co) ----
        {
            #pragma unroll 4
            for (int i = 0; i < 8; ++i) {
                const int a = i * 4 + ca;
                const float w = sTW[wv * 65 + a];
                const int sw = a & 7;
                const char* ra = bufc + a * ROWB;
                const float4 v0 = *(const float4*)(ra + (((2 * co) ^ sw) << 4));
                const float4 v1 = *(const float4*)(ra + (((2 * co + 1) ^ sw) << 4));
                acc8[0] = fmaf(w, v0.x, acc8[0]);
                acc8[1] = fmaf(w, v0.y, acc8[1]);
                acc8[2] = fmaf(w, v0.z, acc8[2]);
                acc8[3] = fmaf(w, v0.w, acc8[3]);
                acc8[4] = fmaf(w, v1.x, acc8[4]);
                acc8[5] = fmaf(w, v1.y, acc8[5]);
                acc8[6] = fmaf(w, v1.z, acc8[6]);
                acc8[7] = fmaf(w, v1.w, acc8[7]);
            }
        }

        // ---- end-of-tile: counted wait (T4) + raw barrier; never vmcnt(0) ----
        if (ti + 1 < nt) {
            if (has2) {
                asm volatile("s_waitcnt vmcnt(4) lgkmcnt(0)" ::: "memory");  // DMA(ti+1) landed
            } else {
                asm volatile("s_waitcnt vmcnt(0) lgkmcnt(0)" ::: "memory");  // drain tail
            }
            __builtin_amdgcn_s_barrier();
        }
        cur = (cur == 2) ? 0 : (cur + 1);
    }

    // ---- epilogue: denom butterfly + reduce over atom-offset lanes ----
    #pragma unroll
    for (int d = 1; d < 64; d <<= 1) s_part += __shfl_xor(s_part, d);
    const float inv = (s_part > 0.0f) ? 1.0f / s_part : 0.0f;
    #pragma unroll
    for (int j = 0; j < 8; ++j) {
        acc8[j] += __shfl_xor(acc8[j], 1);
        acc8[j] += __shfl_xor(acc8[j], 2);
    }
    if ((lane & 3) == 0) {
        float* dst = &gWacc[(size_t)b * 512 + wv * F + (lane >> 2) * 8];
        *(float4*)dst = make_float4(acc8[0] * inv, acc8[1] * inv, acc8[2] * inv, acc8[3] * inv);
        *(float4*)(dst + 4) = make_float4(acc8[4] * inv, acc8[5] * inv, acc8[6] * inv, acc8[7] * inv);
    }
}

// K4: out[b] = silu(Wacc[b] @ Wp + bp). PJC crystals per block; 8-deep Wp
// load batching.
__global__ __launch_bounds__(256) void proj_kernel(
    const float* __restrict__ gWacc, const float* __restrict__ Wp,
    const float* __restrict__ bp, float* __restrict__ out, int B) {
    __shared__ float sW[PJC * 512];   // 8 KB
    __shared__ float sP[256 * PJC];   // 4 KB
    const int t = threadIdx.x;
    const int c0 = blockIdx.x * PJC;
    for (int q = t; q < PJC * 512; q += 256) {
        const int cr = c0 + (q >> 9);
        sW[q] = (cr < B) ? gWacc[(size_t)cr * 512 + (q & 511)] : 0.0f;
    }
    __syncthreads();
    const int f = t & 127, half = t >> 7;
    float acc[PJC] = {};
    const float* wp = Wp + (size_t)(half * 256) * F + f;
    for (int k0 = 0; k0 < 256; k0 += 8) {
        float wpv[8];
        #pragma unroll
        for (int u = 0; u < 8; ++u) wpv[u] = wp[(size_t)(k0 + u) * F];
        #pragma unroll
        for (int u = 0; u < 8; ++u) {
            const int ks = half * 256 + k0 + u;  // wave-uniform -> LDS broadcast
            #pragma unroll
            for (int g = 0; g < PJC; ++g) acc[g] = fmaf(sW[g * 512 + ks], wpv[u], acc[g]);
        }
    }
    #pragma unroll
    for (int g = 0; g < PJC; ++g) sP[t * PJC + g] = acc[g];
    __syncthreads();
    if (t < 128) {
        const float bpf = bp[t];
        #pragma unroll
        for (int g = 0; g < PJC; ++g) {
            const int cr = c0 + g;
            if (cr < B)
                out[(size_t)cr * F + t] =
                    silu_f(sP[t * PJC + g] + sP[(t + 128) * PJC + g] + bpf);
        }
    }
}

extern "C" void kernel_launch(void* const* d_in, const int* in_sizes, int n_in,
                              void* d_out, int out_size, void* d_ws, size_t ws_size,
                              hipStream_t stream) {
    const float* atom_fea = (const float*)d_in[0];
    const int* seg = (const int*)d_in[1];
    const float* W1 = (const float*)d_in[3];
    const float* b1 = (const float*)d_in[4];
    const float* W2 = (const float*)d_in[5];
    const float* b2 = (const float*)d_in[6];
    const float* Wp = (const float*)d_in[7];
    const float* bp = (const float*)d_in[8];
    float* out = (float*)d_out;

    const int N = in_sizes[0] / F;
    const int B = out_size / F;

    // ws layout: starts[B+1] | Wacc[B*512]
    char* ws = (char*)d_ws;
    int* starts = (int*)ws;
    size_t off = (((size_t)(B + 1) * sizeof(int)) + 255) & ~(size_t)255;
    float* gWacc = (float*)(ws + off);

    seg_starts_kernel<<<(N + 255) / 256, 256, 0, stream>>>(seg, starts, N, B);
    fused14_kernel<<<B, 256, 0, stream>>>(atom_fea, starts, W1, b1, W2, b2, gWacc);
    proj_kernel<<<(B + PJC - 1) / PJC, 256, 0, stream>>>(gWacc, Wp, bp, out, B);
}